// Round 1
// baseline (1344.950 us; speedup 1.0000x reference)
//
#include <hip/hip_runtime.h>

// Layout of d_out (all f32): [nids M][means M*128][last_ts M]
// Layout of d_ws: [seg_start M ints][seg_end M ints]

__global__ void init_kernel(const int* __restrict__ nids, float* __restrict__ out_nids,
                            int* __restrict__ seg_start, int* __restrict__ seg_end, int M) {
    int i = blockIdx.x * blockDim.x + threadIdx.x;
    if (i < M) {
        out_nids[i]  = (float)nids[i];
        seg_start[i] = 0;
        seg_end[i]   = 0;  // start==end -> empty segment
    }
}

__global__ void bounds_kernel(const int* __restrict__ seg,
                              int* __restrict__ seg_start, int* __restrict__ seg_end, int N) {
    int i = blockIdx.x * blockDim.x + threadIdx.x;
    if (i >= N) return;
    int s = seg[i];
    if (i == 0     || seg[i - 1] != s) seg_start[s] = i;
    if (i == N - 1 || seg[i + 1] != s) seg_end[s]   = i + 1;  // exclusive
}

// One wave (64 lanes) per segment. D=128 -> each lane owns a float2 column pair.
__global__ void mean_kernel(const float* __restrict__ msgs, const float* __restrict__ ts,
                            const int* __restrict__ seg_start, const int* __restrict__ seg_end,
                            float* __restrict__ out_msgs, float* __restrict__ out_ts, int M) {
    int gtid = blockIdx.x * blockDim.x + threadIdx.x;
    int wave = gtid >> 6;          // wave64
    int lane = threadIdx.x & 63;
    if (wave >= M) return;

    int s   = seg_start[wave];
    int e   = seg_end[wave];
    int cnt = e - s;

    float2 acc = make_float2(0.f, 0.f);
    const float2* base = (const float2*)msgs + (size_t)s * 64 + lane;  // 64 float2 = 128 floats/row
    for (int r = 0; r < cnt; ++r) {
        float2 v = base[(size_t)r * 64];
        acc.x += v.x;
        acc.y += v.y;
    }

    float inv = (cnt > 0) ? (1.0f / (float)cnt) : 0.0f;
    float2* o = (float2*)out_msgs + (size_t)wave * 64 + lane;
    *o = make_float2(acc.x * inv, acc.y * inv);

    if (lane == 0) {
        // last_idx = max pos in segment -> e-1; empty segment clips to index 0
        out_ts[wave] = (cnt > 0) ? ts[e - 1] : ts[0];
    }
}

extern "C" void kernel_launch(void* const* d_in, const int* in_sizes, int n_in,
                              void* d_out, int out_size, void* d_ws, size_t ws_size,
                              hipStream_t stream) {
    const int*   nids = (const int*)  d_in[0];   // [M] int32
    const float* msgs = (const float*)d_in[1];   // [N*128] f32
    const float* ts   = (const float*)d_in[2];   // [N] f32
    const int*   seg  = (const int*)  d_in[3];   // [N] int32, sorted
    // d_in[4] = num_segments scalar; M from in_sizes[0]

    const int M = in_sizes[0];
    const int N = in_sizes[2];

    float* out_nids = (float*)d_out;
    float* out_msgs = out_nids + M;
    float* out_ts   = out_msgs + (size_t)M * 128;

    int* seg_start = (int*)d_ws;
    int* seg_end   = seg_start + M;

    init_kernel  <<<(M + 255) / 256, 256, 0, stream>>>(nids, out_nids, seg_start, seg_end, M);
    bounds_kernel<<<(N + 255) / 256, 256, 0, stream>>>(seg, seg_start, seg_end, N);
    // 4 waves per 256-thread block, one wave per segment
    mean_kernel  <<<(M + 3) / 4, 256, 0, stream>>>(msgs, ts, seg_start, seg_end, out_msgs, out_ts, M);
}